// Round 13
// baseline (644.270 us; speedup 1.0000x reference)
//
#include <hip/hip_runtime.h>
#include <stdint.h>

#define ALPHA 0.3f
#define CLAMPV 0.3f
#define BDIM 4096
#define NDIM 1024

typedef float f32x4 __attribute__((ext_vector_type(4)));
typedef __bf16 bf16x8 __attribute__((ext_vector_type(8)));

union U16x8 { uint4 v; unsigned short u[8]; };
union U16x4 { uint2 v; unsigned short u[4]; };

__device__ __forceinline__ float bf2f(unsigned short u) {
  union { unsigned int i; float f; } c; c.i = ((unsigned int)u) << 16; return c.f;
}
__device__ __forceinline__ unsigned short f2bf(float f) {
  union { float f; unsigned int i; } c; c.f = f;
  unsigned int u = c.i;
  unsigned int r = u + 0x7FFFu + ((u >> 16) & 1u);
  return (unsigned short)(r >> 16);
}

// ---------------------------------------------------------------------------
__global__ __launch_bounds__(256) void fill_k(float* __restrict__ out, int n) {
  int i = blockIdx.x * 256 + threadIdx.x;
  if (i < n) out[i] = 12345.0f;
}

// ---------------------------------------------------------------------------
__global__ __launch_bounds__(256) void split_x_k(const float* __restrict__ x,
                                                 unsigned short* __restrict__ hi,
                                                 unsigned short* __restrict__ lo) {
  const size_t i0 = ((size_t)blockIdx.x * 256 + threadIdx.x) * 8;
  f32x4 a = *(const f32x4*)(x + i0);
  f32x4 b = *(const f32x4*)(x + i0 + 4);
  U16x8 h8, l8;
#pragma unroll
  for (int i = 0; i < 4; ++i) {
    unsigned short h = f2bf(a[i]); h8.u[i] = h; l8.u[i] = f2bf(a[i] - bf2f(h));
    unsigned short h2 = f2bf(b[i]); h8.u[4+i] = h2; l8.u[4+i] = f2bf(b[i] - bf2f(h2));
  }
  *(uint4*)(hi + i0) = h8.v;
  *(uint4*)(lo + i0) = l8.v;
}

// ---------------------------------------------------------------------------
// batched tiled transpose (s2: Weff^T + x^T; s8': h1 -> h1T mode 0)
// ---------------------------------------------------------------------------
struct TDesc {
  const void* in1; const void* in2; const float* Wp;
  unsigned short* out_hi; unsigned short* out_lo;
  int R, C, tilesC, mode;
};
struct TBatch { TDesc d[8]; int start[9]; int n; };

__global__ __launch_bounds__(256) void transpose_k(TBatch batch) {
  const int bid = blockIdx.x;
  int g = 0;
#pragma unroll
  for (int i = 1; i < 8; ++i)
    if (i < batch.n && bid >= batch.start[i]) g = i;
  TDesc D = batch.d[g];
  const int lt = bid - batch.start[g];
  const int trow = lt / D.tilesC;
  const int tcol = lt - trow * D.tilesC;
  const int r0 = trow * 64, c0 = tcol * 64;

  __shared__ float tile[64][65];
  const int t = threadIdx.x;
  const int sub = t >> 3, oct = t & 7;
  const float Wv = (D.mode == 2) ? *D.Wp : 0.f;

#pragma unroll
  for (int p = 0; p < 2; ++p) {
    const int rl = p * 32 + sub;
    const int cl0 = oct * 8;
    float vv[8];
    if (D.mode == 0) {
      const unsigned short* ip = (const unsigned short*)D.in1 + (size_t)(r0 + rl) * D.C + c0 + cl0;
      U16x8 tmp; tmp.v = *(const uint4*)ip;
#pragma unroll
      for (int i = 0; i < 8; ++i) vv[i] = bf2f(tmp.u[i]);
    } else {
      const float* ip = (const float*)D.in1 + (size_t)(r0 + rl) * D.C + c0 + cl0;
      f32x4 a = *(const f32x4*)ip, b = *(const f32x4*)(ip + 4);
#pragma unroll
      for (int i = 0; i < 4; ++i) { vv[i] = a[i]; vv[4+i] = b[i]; }
      if (D.mode == 2) {
        const float* ip2 = (const float*)D.in2 + (size_t)(r0 + rl) * D.C + c0 + cl0;
        f32x4 c = *(const f32x4*)ip2, d2 = *(const f32x4*)(ip2 + 4);
#pragma unroll
        for (int i = 0; i < 4; ++i) { vv[i] += Wv * c[i]; vv[4+i] += Wv * d2[i]; }
      }
    }
#pragma unroll
    for (int i = 0; i < 8; ++i) tile[cl0 + i][rl] = vv[i];
  }
  __syncthreads();
#pragma unroll
  for (int p = 0; p < 2; ++p) {
    const int cl = p * 32 + sub;
    const int rl0 = oct * 8;
    U16x8 h8, l8;
#pragma unroll
    for (int i = 0; i < 8; ++i) {
      float v = tile[cl][rl0 + i];
      unsigned short h = f2bf(v);
      h8.u[i] = h;
      l8.u[i] = f2bf(v - bf2f(h));
    }
    const size_t o = (size_t)(c0 + cl) * D.R + r0 + rl0;
    *(uint4*)(D.out_hi + o) = h8.v;
    if (D.mode != 0) *(uint4*)(D.out_lo + o) = l8.v;
  }
}

// ---------------------------------------------------------------------------
// batched MFMA GEMM v10: K-loop identical to v8/v9 (vmcnt 8/6/0). Fused
// epilogue v2: transposed outputs (tr/spT) now staged through the (dead after
// K-loop) 64KB LDS — exactly one 128col x 256row bf16 tile:
//   scatter: ds_write_b64 at col*256 + (row ^ (fr<<3))  -> 2 lanes/bank, free
//   gather:  per wave 2 cols x 512B, fully coalesced 16B global stores
// v9's direct uint2 scatter (8B @ 8KB stride = 4x store transactions) was the
// round-12 regression. Values bit-identical (same f32 -> f2bf).
// ---------------------------------------------------------------------------
struct GemmDesc {
  const unsigned short *Ahi, *Alo, *Bhi, *Blo;
  int lda, ldb, nk, accadd;     // nk = K/32 steps per phase
  float* out32a;
  float* out32b;
  const float* addin;
  unsigned short* sp_hi;        // row-major split of rv
  unsigned short* sp_lo;
  unsigned short* tr_hi;        // [NDIM][BDIM] transposed split of v
  unsigned short* tr_lo;
  unsigned short* spT_hi;       // [NDIM][BDIM] transposed split of relu(v)
  unsigned short* spT_lo;
};
struct GemmBatch { GemmDesc d[16]; int start[17]; int n; };

#define AS1 __attribute__((address_space(1)))
#define AS3 __attribute__((address_space(3)))

__global__ __launch_bounds__(256, 2) void gemm_k(GemmBatch batch) {
  const int bid = blockIdx.x;
  int g = 0;
#pragma unroll
  for (int i = 1; i < 16; ++i)
    if (i < batch.n && bid >= batch.start[i]) g = i;
  GemmDesc D = batch.d[g];
  const int local = bid - batch.start[g];
  const int tm = local >> 3;        // tilesN fixed at 8 (N=1024)
  const int tn = local & 7;

  // 2 buffers x (A 16KB | Bhi 8KB | Blo 8KB) = 64 KB
  __shared__ __align__(16) unsigned short LDS[32768];

  const int t = threadIdx.x;
  const int lane = t & 63;
  const int wave = t >> 6;
  const int wr = wave >> 1, wc = wave & 1;
  const int fr = lane & 15, fg = lane >> 4;

  f32x4 acc[8][4];
#pragma unroll
  for (int i = 0; i < 8; ++i)
#pragma unroll
    for (int j = 0; j < 4; ++j)
#pragma unroll
      for (int rr = 0; rr < 4; ++rr) acc[i][j][rr] = 0.f;

  // ---- staging geometry (linear LDS dest, pre-swizzled global source) ----
  const int r0 = t >> 2;                                    // 0..63
  const int colSwE = (((t & 3) ^ ((t >> 3) & 3)) << 3);     // element offset

  size_t aRow[4], bRow[2];
#pragma unroll
  for (int qq = 0; qq < 4; ++qq)
    aRow[qq] = (size_t)(tm * 256 + qq * 64 + r0) * D.lda + colSwE;
#pragma unroll
  for (int qq = 0; qq < 2; ++qq)
    bRow[qq] = (size_t)(tn * 128 + qq * 64 + r0) * D.ldb + colSwE;

  const int ldsW = wave * 512;    // wave-uniform elem offset within region

  auto stageA = [&](const unsigned short* P, int kb, int b) {
    unsigned short* base = LDS + b * 16384 + ldsW;
#pragma unroll
    for (int qq = 0; qq < 4; ++qq)
      __builtin_amdgcn_global_load_lds(
          (const AS1 void*)(P + aRow[qq] + kb),
          (AS3 void*)(base + qq * 2048), 16, 0, 0);
  };
  auto stageB = [&](const unsigned short* P, int region, int kb, int b) {
    unsigned short* base = LDS + b * 16384 + region + ldsW;
#pragma unroll
    for (int qq = 0; qq < 2; ++qq)
      __builtin_amdgcn_global_load_lds(
          (const AS1 void*)(P + bRow[qq] + kb),
          (AS3 void*)(base + qq * 2048), 16, 0, 0);
  };

  // ---- fragment ds_read byte offsets (swizzled) ----
  const int swz = ((fg ^ ((fr >> 1) & 3)) << 4);
  int aoff[8], boff[4];
#pragma unroll
  for (int i = 0; i < 8; ++i)
    aoff[i] = (wr * 128 + i * 16 + fr) * 64 + swz;
#pragma unroll
  for (int j = 0; j < 4; ++j)
    boff[j] = 16384 + (wc * 64 + j * 16 + fr) * 64 + swz;
  const char* ldsc = (const char*)LDS;

  auto computePh0 = [&](int b) {
    const char* bb = ldsc + b * 32768;
    bf16x8 af[8];
#pragma unroll
    for (int i = 0; i < 8; ++i) af[i] = *(const bf16x8*)(bb + aoff[i]);
#pragma unroll
    for (int j = 0; j < 4; ++j) {
      const bf16x8 bh = *(const bf16x8*)(bb + boff[j]);
#pragma unroll
      for (int i = 0; i < 8; ++i)
        acc[i][j] = __builtin_amdgcn_mfma_f32_16x16x32_bf16(af[i], bh, acc[i][j], 0, 0, 0);
      const bf16x8 bl = *(const bf16x8*)(bb + boff[j] + 8192);
#pragma unroll
      for (int i = 0; i < 8; ++i)
        acc[i][j] = __builtin_amdgcn_mfma_f32_16x16x32_bf16(af[i], bl, acc[i][j], 0, 0, 0);
    }
  };
  auto computePh1 = [&](int b) {
    const char* bb = ldsc + b * 32768;
    bf16x8 af[8];
#pragma unroll
    for (int i = 0; i < 8; ++i) af[i] = *(const bf16x8*)(bb + aoff[i]);
#pragma unroll
    for (int j = 0; j < 4; ++j) {
      const bf16x8 bh = *(const bf16x8*)(bb + boff[j]);
#pragma unroll
      for (int i = 0; i < 8; ++i)
        acc[i][j] = __builtin_amdgcn_mfma_f32_16x16x32_bf16(af[i], bh, acc[i][j], 0, 0, 0);
    }
  };

  const int n = D.nk;

  // ---- prologue: stage step 0 of phase 0 into buffer 0 (8 loads/wave) ----
  stageA(D.Ahi, 0, 0);
  stageB(D.Bhi, 8192, 0, 0);
  stageB(D.Blo, 12288, 0, 0);
  int buf = 0;

  // ---- phase 0 ----
#pragma unroll 1
  for (int kt = 0; kt < n; ++kt) {
    if (kt + 1 < n) {
      const int kb = (kt + 1) << 5;
      stageA(D.Ahi, kb, buf ^ 1);
      stageB(D.Bhi, 8192, kb, buf ^ 1);
      stageB(D.Blo, 12288, kb, buf ^ 1);
      asm volatile("s_waitcnt vmcnt(8)" ::: "memory");  // drain cur tile, keep 8 prefetch
    } else {
      stageA(D.Alo, 0, buf ^ 1);        // first step of phase 1 (6 loads/wave)
      stageB(D.Bhi, 8192, 0, buf ^ 1);
      asm volatile("s_waitcnt vmcnt(6)" ::: "memory");  // drain cur tile, keep 6 prefetch
    }
    __builtin_amdgcn_s_barrier();
    __builtin_amdgcn_sched_barrier(0);
    computePh0(buf);
    __builtin_amdgcn_sched_barrier(0);
    __builtin_amdgcn_s_barrier();
    buf ^= 1;
  }

  // ---- phase 1 ----
#pragma unroll 1
  for (int kt = 0; kt < n; ++kt) {
    if (kt + 1 < n) {
      const int kb = (kt + 1) << 5;
      stageA(D.Alo, kb, buf ^ 1);
      stageB(D.Bhi, 8192, kb, buf ^ 1);
      asm volatile("s_waitcnt vmcnt(6)" ::: "memory");  // drain cur tile, keep 6 prefetch
    } else {
      asm volatile("s_waitcnt vmcnt(0)" ::: "memory");
    }
    __builtin_amdgcn_s_barrier();
    __builtin_amdgcn_sched_barrier(0);
    computePh1(buf);
    __builtin_amdgcn_sched_barrier(0);
    __builtin_amdgcn_s_barrier();
    buf ^= 1;
  }

  // ---- fused epilogue: row-major outputs (coalesced as before) ----
  const int grb = tm * 256 + wr * 128 + fg * 4;
  const int gcb = tn * 128 + wc * 64 + fr;
#pragma unroll
  for (int i = 0; i < 8; ++i) {
    const int gr0 = grb + i * 16;
#pragma unroll
    for (int j = 0; j < 4; ++j) {
      const int gc = gcb + j * 16;
      const f32x4 v = acc[i][j];
#pragma unroll
      for (int rr = 0; rr < 4; ++rr) {
        const size_t idx = (size_t)(gr0 + rr) * NDIM + gc;
        if (D.out32a) D.out32a[idx] = v[rr];
        if (D.out32b) D.out32b[idx] = D.accadd ? (D.out32b[idx] + v[rr]) : v[rr];
        if (D.sp_hi) {
          const float rv = fmaxf(v[rr] + (D.addin ? D.addin[idx] : 0.f), 0.f);
          const unsigned short h = f2bf(rv);
          D.sp_hi[idx] = h;
          D.sp_lo[idx] = f2bf(rv - bf2f(h));
        }
      }
    }
  }

  // ---- LDS-staged transposed outputs (LDS dead after K-loop) ----
  // LDS tile: 128 cols x 256 rows bf16 = 64KB. Scatter addr:
  //   col*256 + (row ^ ((col&15)<<3))  -> write banks 2 lanes/bank (free).
  // Gather: it-loop, thread t covers col c = it*8 + (t>>5), chunk k = t&31;
  //   LDS data for global rows [k*8, k*8+8) sits at chunk kk = k ^ (c&15).
  //   Wave = 2 cols x 512B contiguous global stores.
  const int colL = wc * 64 + fr;
  const int rowL = wr * 128 + fg * 4;
  auto trStore = [&](unsigned short* dhi, unsigned short* dlo, bool useRelu) {
#pragma unroll 1
    for (int half = 0; half < 2; ++half) {
      __builtin_amdgcn_s_barrier();
#pragma unroll
      for (int i = 0; i < 8; ++i) {
#pragma unroll
        for (int j = 0; j < 4; ++j) {
          const int col = colL + j * 16;
          const int row0 = rowL + i * 16;
          U16x4 q;
#pragma unroll
          for (int rr = 0; rr < 4; ++rr) {
            float xx = acc[i][j][rr];
            if (useRelu) xx = fmaxf(xx, 0.f);
            const unsigned short h = f2bf(xx);
            q.u[rr] = half ? f2bf(xx - bf2f(h)) : h;
          }
          *(uint2*)(LDS + col * 256 + (row0 ^ ((col & 15) << 3))) = q.v;
        }
      }
      __builtin_amdgcn_s_barrier();
      unsigned short* dst = half ? dlo : dhi;
#pragma unroll
      for (int it = 0; it < 16; ++it) {
        const int c = it * 8 + (t >> 5);
        const int k = t & 31;
        const int kk = k ^ (c & 15);
        const uint4 vv = *(const uint4*)(LDS + c * 256 + kk * 8);
        *(uint4*)(dst + (size_t)(tn * 128 + c) * BDIM + (size_t)tm * 256 + k * 8) = vv;
      }
    }
  };
  if (D.tr_hi) trStore(D.tr_hi, D.tr_lo, false);
  if (D.spT_hi) trStore(D.spT_hi, D.spT_lo, true);
}

// ---------------------------------------------------------------------------
// batched heb reduction: out = clamp(heb_in + ALPHA * sum(parts)), 1024
// blocks per desc.
// ---------------------------------------------------------------------------
struct HebRedB {
  const float* heb_in[3]; float* outp[3];
  const float* p[3][16]; int np[3]; int n;
};

__global__ __launch_bounds__(256) void hebred_k(HebRedB B) {
  const int g = blockIdx.x >> 10;
  const int local = blockIdx.x & 1023;
  const size_t i0 = ((size_t)local * 256 + threadIdx.x) * 4;
  f32x4 s = *(const f32x4*)(B.p[g][0] + i0);
#pragma unroll
  for (int k = 1; k < 16; ++k)
    if (k < B.np[g]) s += *(const f32x4*)(B.p[g][k] + i0);
  f32x4 h = *(const f32x4*)(B.heb_in[g] + i0);
  f32x4 o;
#pragma unroll
  for (int i = 0; i < 4; ++i) o[i] = fminf(fmaxf(h[i] + ALPHA * s[i], -CLAMPV), CLAMPV);
  *(f32x4*)(B.outp[g] + i0) = o;
}

// ---------------------------------------------------------------------------
__global__ __launch_bounds__(256) void yassm_k(const float* __restrict__ ysum,
                                               float* __restrict__ yout) {
  const int stride = gridDim.x * 256;
  for (int idx = blockIdx.x * 256 + threadIdx.x; idx < BDIM * 1022; idx += stride) {
    const int row = idx / 1022;
    const int col = idx - row * 1022;
    yout[idx] = ysum[(size_t)row * NDIM + col];
  }
}

__global__ __launch_bounds__(256) void tanhcol_k(const float* __restrict__ ysum,
                                                 float* __restrict__ wpart,
                                                 float* __restrict__ dpart) {
  const int r = blockIdx.x * 256 + threadIdx.x;
  const size_t b = (size_t)r * NDIM;
  float tw = tanhf(ysum[b + 1022]);
  float td = tanhf(ysum[b + 1021]);
#pragma unroll
  for (int o = 32; o > 0; o >>= 1) { tw += __shfl_down(tw, o); td += __shfl_down(td, o); }
  __shared__ float s1[4], s2[4];
  const int lane = threadIdx.x & 63, wv = threadIdx.x >> 6;
  if (lane == 0) { s1[wv] = tw; s2[wv] = td; }
  __syncthreads();
  if (threadIdx.x == 0) {
    wpart[blockIdx.x] = s1[0] + s1[1] + s1[2] + s1[3];
    dpart[blockIdx.x] = s2[0] + s2[1] + s2[2] + s2[3];
  }
}

__global__ void finalize_k(const float* __restrict__ wpart, const float* __restrict__ dpart,
                           float* __restrict__ out, int nout) {
  if (threadIdx.x == 0 && blockIdx.x == 0) {
    float s = 0.f, d = 0.f;
    for (int i = 0; i < 16; ++i) { s += wpart[i]; d += dpart[i]; }
    out[nout - 2] = s * (1.f / BDIM);
    out[nout - 1] = d * (1.f / BDIM);
  }
}

// ---------------------------------------------------------------------------
extern "C" void kernel_launch(void* const* d_in, const int* in_sizes, int n_in,
                              void* d_out, int out_size, void* d_ws, size_t ws_size,
                              hipStream_t stream) {
  const float* x = (const float*)d_in[0];
  const float* wbase[6]; const float* hebin[6];
  for (int i = 0; i < 6; ++i) { wbase[i] = (const float*)d_in[1 + i]; hebin[i] = (const float*)d_in[7 + i]; }
  const float* Wp = (const float*)d_in[13];
  float* out = (float*)d_out;
  const size_t YOUT = (size_t)BDIM * 1022;
  float* hebout[6];
  for (int i = 0; i < 6; ++i) hebout[i] = out + YOUT + (size_t)i * 1048576;

  // ---- workspace: 9 PAIR regions + 6 weight pairs + 2 f32 = 200 MiB ----
  const size_t E = (size_t)BDIM * NDIM;
  const size_t PAIRB = E * 4;                    // hi+lo bf16 pair (16 MiB)
  const size_t WPAIRB = (size_t)NDIM * NDIM * 4; // weight hi+lo pair (4 MiB)
  const size_t FB = E * 4;                       // f32 buffer (16 MiB)
  const size_t REQUIRED = 9 * PAIRB + 6 * WPAIRB + 2 * FB;   // 200 MiB

  if (ws_size < REQUIRED) {
    fill_k<<<(out_size + 255) / 256, 256, 0, stream>>>(out, out_size);
    return;
  }

  char* p = (char*)d_ws;
  auto takeB = [&](size_t n) -> char* { char* q = p; p += n; return q; };

  // lifetime-aliased regions (all transitions audited per dispatch):
  unsigned short* P0 = (unsigned short*)takeB(PAIRB);  // x pair -> h1 pair (s5)
  unsigned short* P1 = (unsigned short*)takeB(PAIRB);  // xT pair (dead after s5)
  unsigned short* P2 = (unsigned short*)takeB(PAIRB);  // h0 pair -> s7 part slot -> s9 parts 0-3
  unsigned short* P3 = (unsigned short*)takeB(PAIRB);  // h0T pair -> s9 parts 4-7
  unsigned short* P4 = (unsigned short*)takeB(PAIRB);  // fT0 -> h1T (s8')
  unsigned short* P5 = (unsigned short*)takeB(PAIRB);  // fT1 -> fT5 (s7)
  unsigned short* P6 = (unsigned short*)takeB(PAIRB);  // fT3 -> s9 parts 8-11
  unsigned short* P7 = (unsigned short*)takeB(PAIRB);  // fT2 (s5) -> s9 parts 12-15
  unsigned short* P8 = (unsigned short*)takeB(PAIRB);  // fT4 (s5) -> wpart/dpart
  unsigned short* WThi[6]; unsigned short* WTlo[6];
  for (int i = 0; i < 6; ++i) {
    WThi[i] = (unsigned short*)takeB(WPAIRB);
    WTlo[i] = WThi[i] + (size_t)NDIM * NDIM;
  }
  float* F1 = (float*)takeB(FB);   // h1x f32 (addin for h10)
  float* F3 = (float*)takeB(FB);   // ysum (live to end)

  unsigned short *xhi = P0, *xlo = P0 + E;
  unsigned short *xThi = P1, *xTlo = P1 + E;
  unsigned short *h0hi = P2, *h0lo = P2 + E;
  unsigned short *h0Thi = P3, *h0Tlo = P3 + E;
  float* wpart = (float*)P8; float* dpart = wpart + 64;  // P8 free after s7

  // ---- s1: split x ----
  split_x_k<<<2048, 256, 0, stream>>>(x, xhi, xlo);

  // ---- s2: Weff^T splits (6) + x^T split ----
  {
    TBatch tb{};
    int s = 0;
    for (int i = 0; i < 6; ++i) {
      tb.d[i] = { wbase[i], hebin[i], Wp, WThi[i], WTlo[i], NDIM, NDIM, NDIM / 64, 2 };
      tb.start[i] = s; s += (NDIM / 64) * (NDIM / 64);
    }
    tb.d[6] = { x, nullptr, nullptr, xThi, xTlo, BDIM, NDIM, NDIM / 64, 1 };
    tb.start[6] = s; s += (BDIM / 64) * (NDIM / 64);
    tb.start[7] = s; tb.n = 7;
    transpose_k<<<s, 256, 0, stream>>>(tb);
  }

  auto fwdDesc = [&](const unsigned short* ahi, const unsigned short* alo, int wi) -> GemmDesc {
    GemmDesc d{};
    d.Ahi = ahi; d.Alo = alo; d.Bhi = WThi[wi]; d.Blo = WTlo[wi];
    d.lda = NDIM; d.ldb = NDIM; d.nk = NDIM / 32;
    return d;
  };
  auto hebPart = [&](const unsigned short* ahi, const unsigned short* alo,
                     const unsigned short* bhi, const unsigned short* blo,
                     int koff, int klen, float* partOut) -> GemmDesc {
    GemmDesc d{};
    d.Ahi = ahi + koff; d.Alo = alo + koff;
    d.Bhi = bhi + koff; d.Blo = blo + koff;
    d.lda = BDIM; d.ldb = BDIM; d.nk = klen / 32;
    d.out32a = partOut;
    return d;
  };

  // ---- s3: h0x, h1x, yx (384 blocks) with fused transposed outputs ----
  {
    GemmBatch gb{};
    gb.d[0] = fwdDesc(xhi, xlo, 0);                 // h0x
    gb.d[0].sp_hi = h0hi; gb.d[0].sp_lo = h0lo;     // h0 = relu(h0x) split
    gb.d[0].tr_hi = P4; gb.d[0].tr_lo = P4 + E;     // fT0 = h0x^T split
    gb.d[0].spT_hi = h0Thi; gb.d[0].spT_lo = h0Tlo; // h0T
    gb.d[1] = fwdDesc(xhi, xlo, 1);                 // h1x
    gb.d[1].out32a = F1;
    gb.d[1].tr_hi = P5; gb.d[1].tr_lo = P5 + E;     // fT1 = h1x^T split
    gb.d[2] = fwdDesc(xhi, xlo, 3);                 // yx
    gb.d[2].out32b = F3; gb.d[2].accadd = 0;
    gb.d[2].tr_hi = P6; gb.d[2].tr_lo = P6 + E;     // fT3 = yx^T split
    gb.start[0] = 0; gb.start[1] = 128; gb.start[2] = 256; gb.start[3] = 384;
    gb.n = 3;
    gemm_k<<<384, 256, 0, stream>>>(gb);
  }

  // ---- s5: heb{x2h0,x2h1,x2y} 2-way split-K + h10, y0 (448 blocks) ----
  {
    float* px0a = (float*)WThi[0]; float* px0b = hebout[0];
    float* px1a = (float*)WThi[1]; float* px1b = hebout[1];
    float* pxya = (float*)WThi[3]; float* pxyb = hebout[3];
    GemmBatch gb{};
    gb.d[0] = hebPart(xThi, xTlo, P4, P4 + E, 0,    2048, px0a);  // x2h0
    gb.d[1] = hebPart(xThi, xTlo, P4, P4 + E, 2048, 2048, px0b);
    gb.d[2] = hebPart(xThi, xTlo, P5, P5 + E, 0,    2048, px1a);  // x2h1
    gb.d[3] = hebPart(xThi, xTlo, P5, P5 + E, 2048, 2048, px1b);
    gb.d[4] = hebPart(xThi, xTlo, P6, P6 + E, 0,    2048, pxya);  // x2y
    gb.d[5] = hebPart(xThi, xTlo, P6, P6 + E, 2048, 2048, pxyb);
    gb.d[6] = fwdDesc(h0hi, h0lo, 2);               // h1_0
    gb.d[6].addin = F1;
    gb.d[6].sp_hi = P0; gb.d[6].sp_lo = P0 + E;     // h1 = relu(h1x+h10) split
    gb.d[6].tr_hi = P7; gb.d[6].tr_lo = P7 + E;     // fT2 = h10^T split
    gb.d[7] = fwdDesc(h0hi, h0lo, 4);               // y0
    gb.d[7].out32b = F3; gb.d[7].accadd = 1;
    gb.d[7].tr_hi = P8; gb.d[7].tr_lo = P8 + E;     // fT4 = y0^T split
    for (int i = 0; i < 6; ++i) gb.start[i] = i * 32;
    gb.start[6] = 192; gb.start[7] = 320; gb.start[8] = 448;
    gb.n = 8;
    gemm_k<<<448, 256, 0, stream>>>(gb);
    HebRedB rb{};
    rb.heb_in[0] = hebin[0]; rb.outp[0] = hebout[0]; rb.p[0][0] = px0a; rb.p[0][1] = px0b; rb.np[0] = 2;
    rb.heb_in[1] = hebin[1]; rb.outp[1] = hebout[1]; rb.p[1][0] = px1a; rb.p[1][1] = px1b; rb.np[1] = 2;
    rb.heb_in[2] = hebin[3]; rb.outp[2] = hebout[3]; rb.p[2][0] = pxya; rb.p[2][1] = pxyb; rb.np[2] = 2;
    rb.n = 3;
    hebred_k<<<3072, 256, 0, stream>>>(rb);
  }

  // ---- s8': h1 -> h1T (bf16 pair transpose into P4; fT0 dead) ----
  {
    TBatch tb{};
    tb.d[0] = { P0,     nullptr, nullptr, P4,     nullptr, BDIM, NDIM, NDIM / 64, 0 };
    tb.d[1] = { P0 + E, nullptr, nullptr, P4 + E, nullptr, BDIM, NDIM, NDIM / 64, 0 };
    tb.start[0] = 0; tb.start[1] = 1024; tb.start[2] = 2048; tb.n = 2;
    transpose_k<<<2048, 256, 0, stream>>>(tb);
  }

  // ---- s7: heb{h02h1,h02y} 4-way split-K + y1 (384 blocks) ----
  {
    float* pa[4] = { (float*)WThi[0], (float*)WThi[1], (float*)WThi[2], hebout[2] };
    float* pb[4] = { (float*)WThi[3], (float*)WThi[4], (float*)P2, hebout[4] };
    GemmBatch gb{};
    for (int h = 0; h < 4; ++h) {
      gb.d[h]     = hebPart(h0Thi, h0Tlo, P7, P7 + E, h * 1024, 1024, pa[h]); // h02h1
      gb.d[4 + h] = hebPart(h0Thi, h0Tlo, P8, P8 + E, h * 1024, 1024, pb[h]); // h02y
    }
    gb.d[8] = fwdDesc(P0, P0 + E, 5);               // y1 (A = h1 pair)
    gb.d[8].out32b = F3; gb.d[8].accadd = 1;
    gb.d[8].tr_hi = P5; gb.d[8].tr_lo = P5 + E;     // fT5 = y1^T split (fT1 dead)
    for (int i = 0; i < 8; ++i) gb.start[i] = i * 32;
    gb.start[8] = 256; gb.start[9] = 384;
    gb.n = 9;
    gemm_k<<<384, 256, 0, stream>>>(gb);
    HebRedB rb{};
    rb.heb_in[0] = hebin[2]; rb.outp[0] = hebout[2];
    for (int h = 0; h < 4; ++h) rb.p[0][h] = pa[h];
    rb.np[0] = 4;
    rb.heb_in[1] = hebin[4]; rb.outp[1] = hebout[4];
    for (int h = 0; h < 4; ++h) rb.p[1][h] = pb[h];
    rb.np[1] = 4;
    rb.n = 2;
    hebred_k<<<2048, 256, 0, stream>>>(rb);
  }

  // ---- s9: heb_h12y 16-way split-K (512 blocks) ----
  // partials: P2 (h0 dead), P3 (h0T dead), P6 (fT3 dead), P7 (fT2 dead)
  {
    float* parts[16];
    for (int h = 0; h < 4; ++h) {
      parts[h]      = (float*)P2 + (size_t)h * 1048576;
      parts[4 + h]  = (float*)P3 + (size_t)h * 1048576;
      parts[8 + h]  = (float*)P6 + (size_t)h * 1048576;
      parts[12 + h] = (float*)P7 + (size_t)h * 1048576;
    }
    GemmBatch gb{};
    for (int h = 0; h < 16; ++h)
      gb.d[h] = hebPart(P4, P4 + E, P5, P5 + E, h * 256, 256, parts[h]);
    for (int i = 0; i <= 16; ++i) gb.start[i] = i * 32;
    gb.n = 16;
    gemm_k<<<512, 256, 0, stream>>>(gb);
    HebRedB rb{};
    rb.heb_in[0] = hebin[5]; rb.outp[0] = hebout[5];
    for (int h = 0; h < 16; ++h) rb.p[0][h] = parts[h];
    rb.np[0] = 16;
    rb.n = 1;
    hebred_k<<<1024, 256, 0, stream>>>(rb);
  }

  // ---- s10: y assembly, tanh means (wpart in P8; fT4 dead after s7) ----
  yassm_k<<<2048, 256, 0, stream>>>(F3, out);
  tanhcol_k<<<16, 256, 0, stream>>>(F3, wpart, dpart);
  finalize_k<<<1, 64, 0, stream>>>(wpart, dpart, out, out_size);
}

// Round 14
// 501.327 us; speedup vs baseline: 1.2851x; 1.2851x over previous
//
#include <hip/hip_runtime.h>
#include <stdint.h>

#define ALPHA 0.3f
#define CLAMPV 0.3f
#define BDIM 4096
#define NDIM 1024

typedef float f32x4 __attribute__((ext_vector_type(4)));
typedef __bf16 bf16x8 __attribute__((ext_vector_type(8)));

union U16x8 { uint4 v; unsigned short u[8]; };

__device__ __forceinline__ float bf2f(unsigned short u) {
  union { unsigned int i; float f; } c; c.i = ((unsigned int)u) << 16; return c.f;
}
__device__ __forceinline__ unsigned short f2bf(float f) {
  union { float f; unsigned int i; } c; c.f = f;
  unsigned int u = c.i;
  unsigned int r = u + 0x7FFFu + ((u >> 16) & 1u);
  return (unsigned short)(r >> 16);
}

// ---------------------------------------------------------------------------
__global__ __launch_bounds__(256) void fill_k(float* __restrict__ out, int n) {
  int i = blockIdx.x * 256 + threadIdx.x;
  if (i < n) out[i] = 12345.0f;
}

// ---------------------------------------------------------------------------
__global__ __launch_bounds__(256) void split_x_k(const float* __restrict__ x,
                                                 unsigned short* __restrict__ hi,
                                                 unsigned short* __restrict__ lo) {
  const size_t i0 = ((size_t)blockIdx.x * 256 + threadIdx.x) * 8;
  f32x4 a = *(const f32x4*)(x + i0);
  f32x4 b = *(const f32x4*)(x + i0 + 4);
  U16x8 h8, l8;
#pragma unroll
  for (int i = 0; i < 4; ++i) {
    unsigned short h = f2bf(a[i]); h8.u[i] = h; l8.u[i] = f2bf(a[i] - bf2f(h));
    unsigned short h2 = f2bf(b[i]); h8.u[4+i] = h2; l8.u[4+i] = f2bf(b[i] - bf2f(h2));
  }
  *(uint4*)(hi + i0) = h8.v;
  *(uint4*)(lo + i0) = l8.v;
}

// ---------------------------------------------------------------------------
// batched tiled transpose
// ---------------------------------------------------------------------------
struct TDesc {
  const void* in1; const void* in2; const float* Wp;
  unsigned short* out_hi; unsigned short* out_lo;
  int R, C, tilesC, mode;
};
struct TBatch { TDesc d[8]; int start[9]; int n; };

__global__ __launch_bounds__(256) void transpose_k(TBatch batch) {
  const int bid = blockIdx.x;
  int g = 0;
#pragma unroll
  for (int i = 1; i < 8; ++i)
    if (i < batch.n && bid >= batch.start[i]) g = i;
  TDesc D = batch.d[g];
  const int lt = bid - batch.start[g];
  const int trow = lt / D.tilesC;
  const int tcol = lt - trow * D.tilesC;
  const int r0 = trow * 64, c0 = tcol * 64;

  __shared__ float tile[64][65];
  const int t = threadIdx.x;
  const int sub = t >> 3, oct = t & 7;
  const float Wv = (D.mode == 2) ? *D.Wp : 0.f;

#pragma unroll
  for (int p = 0; p < 2; ++p) {
    const int rl = p * 32 + sub;
    const int cl0 = oct * 8;
    float vv[8];
    if (D.mode == 0) {
      const unsigned short* ip = (const unsigned short*)D.in1 + (size_t)(r0 + rl) * D.C + c0 + cl0;
      U16x8 tmp; tmp.v = *(const uint4*)ip;
#pragma unroll
      for (int i = 0; i < 8; ++i) vv[i] = bf2f(tmp.u[i]);
    } else {
      const float* ip = (const float*)D.in1 + (size_t)(r0 + rl) * D.C + c0 + cl0;
      f32x4 a = *(const f32x4*)ip, b = *(const f32x4*)(ip + 4);
#pragma unroll
      for (int i = 0; i < 4; ++i) { vv[i] = a[i]; vv[4+i] = b[i]; }
      if (D.mode == 2) {
        const float* ip2 = (const float*)D.in2 + (size_t)(r0 + rl) * D.C + c0 + cl0;
        f32x4 c = *(const f32x4*)ip2, d2 = *(const f32x4*)(ip2 + 4);
#pragma unroll
        for (int i = 0; i < 4; ++i) { vv[i] += Wv * c[i]; vv[4+i] += Wv * d2[i]; }
      }
    }
#pragma unroll
    for (int i = 0; i < 8; ++i) tile[cl0 + i][rl] = vv[i];
  }
  __syncthreads();
#pragma unroll
  for (int p = 0; p < 2; ++p) {
    const int cl = p * 32 + sub;
    const int rl0 = oct * 8;
    U16x8 h8, l8;
#pragma unroll
    for (int i = 0; i < 8; ++i) {
      float v = tile[cl][rl0 + i];
      unsigned short h = f2bf(v);
      h8.u[i] = h;
      l8.u[i] = f2bf(v - bf2f(h));
    }
    const size_t o = (size_t)(c0 + cl) * D.R + r0 + rl0;
    *(uint4*)(D.out_hi + o) = h8.v;
    if (D.mode != 0) *(uint4*)(D.out_lo + o) = l8.v;
  }
}

// ---------------------------------------------------------------------------
// batched MFMA GEMM v4 (RESTORED from round 7 = best total 502 us):
// 128x128 tile, BK=64, 4 waves, fused split-bf16.
//   phase 0: stage {Ahi, Bhi, Blo} (48KB) -> Ahi*Bhi + Ahi*Blo  (64 MFMA/wave)
//   phase 1: stage {Alo, Bhi}             -> Alo*Bhi            (32 MFMA/wave)
// Single-buffered, one stage+drain per BK=64 step. 48KB LDS -> 3 blocks/CU.
// Linear LDS (128B rows) + 3-bit XOR swizzle both sides.
// Post-r13 note: rounds 8-13 tried 256-tile dbuf+counted-vmcnt (faster
// dispatches, worse totals from grid tails) and fused-transpose epilogues
// (both regressed). This v4 config is the measured optimum of the family.
// ---------------------------------------------------------------------------
struct GemmDesc {
  const unsigned short *Ahi, *Alo, *Bhi, *Blo;
  int lda, ldb, nk, accadd;     // nk = K/64 steps per phase
  float* out32a;
  float* out32b;
  const float* addin;
  unsigned short* sp_hi;
  unsigned short* sp_lo;
  const float* heb_in;
  float* heb_out;
};
struct GemmBatch { GemmDesc d[12]; int start[13]; int n; };

__global__ __launch_bounds__(256) void gemm_k(GemmBatch batch) {
  const int bid = blockIdx.x;
  int g = 0;
#pragma unroll
  for (int i = 1; i < 12; ++i)
    if (i < batch.n && bid >= batch.start[i]) g = i;
  GemmDesc D = batch.d[g];
  const int local = bid - batch.start[g];
  const int tm = local >> 3;        // tilesN fixed at 8 (N=1024)
  const int tn = local & 7;

  __shared__ __align__(16) unsigned short As[128 * 64];    // 16 KB
  __shared__ __align__(16) unsigned short BsH[128 * 64];   // 16 KB
  __shared__ __align__(16) unsigned short BsL[128 * 64];   // 16 KB

  const int t = threadIdx.x;
  const int lane = t & 63;
  const int wave = t >> 6;
  const int wr = wave >> 1, wc = wave & 1;
  const int fr = lane & 15, fg = lane >> 4;

  const f32x4 vzero = {0.f, 0.f, 0.f, 0.f};
  f32x4 acc[4][4];
#pragma unroll
  for (int i = 0; i < 4; ++i)
#pragma unroll
    for (int j = 0; j < 4; ++j) acc[i][j] = vzero;

  // staging geometry: rows are 128B; thread t covers rows srow+32q, bytes
  // [scolB, scolB+16) where scolB is the 3-bit XOR pre-swizzled column.
  const int srow = t >> 3;                                   // 0..31
  const int scolB = ((t & 7) << 4) ^ ((srow & 7) << 4);      // bytes in row
  const int scolE = scolB >> 1;                              // elems

  // fragment ds_read byte offsets (s=0 slice; slice 1 = ^0x40)
  int aoff[4], boff[4];
#pragma unroll
  for (int i = 0; i < 4; ++i) {
    const int ra = wr * 64 + i * 16 + fr;
    aoff[i] = ra * 128 + ((fg << 4) ^ ((ra & 7) << 4));
    const int rb = wc * 64 + i * 16 + fr;
    boff[i] = rb * 128 + ((fg << 4) ^ ((rb & 7) << 4));
  }
  const char* Asb = (const char*)As;
  const char* BsHb = (const char*)BsH;
  const char* BsLb = (const char*)BsL;

  const size_t arow = (size_t)(tm * 128 + srow) * D.lda + scolE;
  const size_t brow = (size_t)(tn * 128 + srow) * D.ldb + scolE;
  const size_t astep = (size_t)32 * D.lda;
  const size_t bstep = (size_t)32 * D.ldb;

#pragma unroll 1
  for (int ph = 0; ph < 2; ++ph) {
    const unsigned short* Ap = ph ? D.Alo : D.Ahi;
#pragma unroll 1
    for (int kt = 0; kt < D.nk; ++kt) {
      const int kb = kt << 6;   // k-elem offset
      // ---- stage (12 loads phase0, 8 loads phase1) ----
#pragma unroll
      for (int q = 0; q < 4; ++q) {
        __builtin_amdgcn_global_load_lds(
            (const __attribute__((address_space(1))) void*)(Ap + arow + q * astep + kb),
            (__attribute__((address_space(3))) void*)(As + q * 2048 + wave * 512), 16, 0, 0);
        __builtin_amdgcn_global_load_lds(
            (const __attribute__((address_space(1))) void*)(D.Bhi + brow + q * bstep + kb),
            (__attribute__((address_space(3))) void*)(BsH + q * 2048 + wave * 512), 16, 0, 0);
      }
      if (ph == 0) {
#pragma unroll
        for (int q = 0; q < 4; ++q)
          __builtin_amdgcn_global_load_lds(
              (const __attribute__((address_space(1))) void*)(D.Blo + brow + q * bstep + kb),
              (__attribute__((address_space(3))) void*)(BsL + q * 2048 + wave * 512), 16, 0, 0);
      }
      __syncthreads();           // drain stage, rendezvous
      // ---- compute: 2 k-slices of 32 ----
#pragma unroll
      for (int s = 0; s < 2; ++s) {
        const int sx = s << 6;
        bf16x8 af[4];
#pragma unroll
        for (int i = 0; i < 4; ++i) af[i] = *(const bf16x8*)(Asb + (aoff[i] ^ sx));
#pragma unroll
        for (int j = 0; j < 4; ++j) {
          const bf16x8 bh = *(const bf16x8*)(BsHb + (boff[j] ^ sx));
#pragma unroll
          for (int i = 0; i < 4; ++i)
            acc[i][j] = __builtin_amdgcn_mfma_f32_16x16x32_bf16(af[i], bh, acc[i][j], 0, 0, 0);
          if (ph == 0) {
            const bf16x8 bl = *(const bf16x8*)(BsLb + (boff[j] ^ sx));
#pragma unroll
            for (int i = 0; i < 4; ++i)
              acc[i][j] = __builtin_amdgcn_mfma_f32_16x16x32_bf16(af[i], bl, acc[i][j], 0, 0, 0);
          }
        }
      }
      __syncthreads();           // all reads done before next stage
    }
  }

  const int grb = tm * 128 + wr * 64 + fg * 4;
  const int gcb = tn * 128 + wc * 64 + fr;
#pragma unroll
  for (int i = 0; i < 4; ++i) {
#pragma unroll
    for (int j = 0; j < 4; ++j) {
      const int gc = gcb + j * 16;
#pragma unroll
      for (int r = 0; r < 4; ++r) {
        const int gr = grb + i * 16 + r;
        const size_t idx = (size_t)gr * NDIM + gc;
        const float v = acc[i][j][r];
        if (D.heb_out) {
          D.heb_out[idx] = fminf(fmaxf(D.heb_in[idx] + ALPHA * v, -CLAMPV), CLAMPV);
        } else {
          if (D.out32a) D.out32a[idx] = v;
          if (D.out32b) D.out32b[idx] = D.accadd ? (D.out32b[idx] + v) : v;
          if (D.sp_hi) {
            float rv = v + (D.addin ? D.addin[idx] : 0.f);
            rv = fmaxf(rv, 0.f);
            const unsigned short h = f2bf(rv);
            D.sp_hi[idx] = h;
            D.sp_lo[idx] = f2bf(rv - bf2f(h));
          }
        }
      }
    }
  }
}

// ---------------------------------------------------------------------------
// heb output from up to 8 split-K partials: out = clamp(heb_in + ALPHA*sum)
// ---------------------------------------------------------------------------
struct HebRed { const float* heb_in; float* out; const float* p[8]; int np; };

__global__ __launch_bounds__(256) void hebred_k(HebRed R) {
  const size_t i0 = ((size_t)blockIdx.x * 256 + threadIdx.x) * 4;
  f32x4 s = *(const f32x4*)(R.p[0] + i0);
#pragma unroll
  for (int k = 1; k < 8; ++k)
    if (k < R.np) s += *(const f32x4*)(R.p[k] + i0);
  f32x4 h = *(const f32x4*)(R.heb_in + i0);
  f32x4 o;
#pragma unroll
  for (int i = 0; i < 4; ++i) o[i] = fminf(fmaxf(h[i] + ALPHA * s[i], -CLAMPV), CLAMPV);
  *(f32x4*)(R.out + i0) = o;
}

// ---------------------------------------------------------------------------
__global__ __launch_bounds__(256) void yassm_k(const float* __restrict__ ysum,
                                               float* __restrict__ yout) {
  const int stride = gridDim.x * 256;
  for (int idx = blockIdx.x * 256 + threadIdx.x; idx < BDIM * 1022; idx += stride) {
    const int row = idx / 1022;
    const int col = idx - row * 1022;
    yout[idx] = ysum[(size_t)row * NDIM + col];
  }
}

__global__ __launch_bounds__(256) void tanhcol_k(const float* __restrict__ ysum,
                                                 float* __restrict__ wpart,
                                                 float* __restrict__ dpart) {
  const int r = blockIdx.x * 256 + threadIdx.x;
  const size_t b = (size_t)r * NDIM;
  float tw = tanhf(ysum[b + 1022]);
  float td = tanhf(ysum[b + 1021]);
#pragma unroll
  for (int o = 32; o > 0; o >>= 1) { tw += __shfl_down(tw, o); td += __shfl_down(td, o); }
  __shared__ float s1[4], s2[4];
  const int lane = threadIdx.x & 63, wv = threadIdx.x >> 6;
  if (lane == 0) { s1[wv] = tw; s2[wv] = td; }
  __syncthreads();
  if (threadIdx.x == 0) {
    wpart[blockIdx.x] = s1[0] + s1[1] + s1[2] + s1[3];
    dpart[blockIdx.x] = s2[0] + s2[1] + s2[2] + s2[3];
  }
}

__global__ void finalize_k(const float* __restrict__ wpart, const float* __restrict__ dpart,
                           float* __restrict__ out, int nout) {
  if (threadIdx.x == 0 && blockIdx.x == 0) {
    float s = 0.f, d = 0.f;
    for (int i = 0; i < 16; ++i) { s += wpart[i]; d += dpart[i]; }
    out[nout - 2] = s * (1.f / BDIM);
    out[nout - 1] = d * (1.f / BDIM);
  }
}

// ---------------------------------------------------------------------------
extern "C" void kernel_launch(void* const* d_in, const int* in_sizes, int n_in,
                              void* d_out, int out_size, void* d_ws, size_t ws_size,
                              hipStream_t stream) {
  const float* x = (const float*)d_in[0];
  const float* wbase[6]; const float* hebin[6];
  for (int i = 0; i < 6; ++i) { wbase[i] = (const float*)d_in[1 + i]; hebin[i] = (const float*)d_in[7 + i]; }
  const float* Wp = (const float*)d_in[13];
  float* out = (float*)d_out;
  const size_t YOUT = (size_t)BDIM * 1022;
  float* hebout[6];
  for (int i = 0; i < 6; ++i) hebout[i] = out + YOUT + (size_t)i * 1048576;

  // ---- workspace layout: 200 MiB, lifetime-aliased regions ----
  const size_t E = (size_t)BDIM * NDIM;
  const size_t PAIRB = E * 4;                    // hi+lo bf16 pair (16 MiB)
  const size_t WPAIRB = (size_t)NDIM * NDIM * 4; // weight hi+lo pair (4 MiB)
  const size_t FB = E * 4;                       // f32 buffer (16 MiB)
  const size_t REQUIRED = 7 * PAIRB + 6 * WPAIRB + 4 * FB;

  if (ws_size < REQUIRED) {
    fill_k<<<(out_size + 255) / 256, 256, 0, stream>>>(out, out_size);
    return;
  }

  char* p = (char*)d_ws;
  auto takeB = [&](size_t n) -> char* { char* q = p; p += n; return q; };

  unsigned short* R0 = (unsigned short*)takeB(PAIRB);   // x pair -> h1 pair
  unsigned short* R1 = (unsigned short*)takeB(PAIRB);   // xT pair -> h1T pair
  unsigned short* R2 = (unsigned short*)takeB(PAIRB);   // h0 pair -> fT5 pair
  unsigned short* R3 = (unsigned short*)takeB(PAIRB);   // h0T pair
  unsigned short* R4 = (unsigned short*)takeB(PAIRB);   // fT0 -> fT2 -> h12y parts 0-3
  unsigned short* R5 = (unsigned short*)takeB(PAIRB);   // fT1 -> fT4 -> h12y parts 4-7
  unsigned short* R6 = (unsigned short*)takeB(PAIRB);   // fT3 -> h02y parts -> wpart
  unsigned short* WThi[6]; unsigned short* WTlo[6];
  for (int i = 0; i < 6; ++i) {
    WThi[i] = (unsigned short*)takeB(WPAIRB);
    WTlo[i] = WThi[i] + (size_t)NDIM * NDIM;
  }
  float* F0 = (float*)takeB(FB);   // h0x -> h10
  float* F1 = (float*)takeB(FB);   // h1x -> y1tmp
  float* F2 = (float*)takeB(FB);   // yxtmp -> y0tmp
  float* F3 = (float*)takeB(FB);   // ysum (live to end)

  unsigned short *xhi = R0, *xlo = R0 + E;
  unsigned short *xThi = R1, *xTlo = R1 + E;
  unsigned short *h0hi = R2, *h0lo = R2 + E;
  unsigned short *h0Thi = R3, *h0Tlo = R3 + E;
  float* part = (float*)R4;        // h12y: 8 x 1M f32 spans R4+R5
  float* wpart = (float*)R6; float* dpart = wpart + 64;

  // ---- s1: split x ----
  split_x_k<<<2048, 256, 0, stream>>>(x, xhi, xlo);

  // ---- s2: Weff^T splits (6) + x^T split ----
  {
    TBatch tb{};
    int s = 0;
    for (int i = 0; i < 6; ++i) {
      tb.d[i] = { wbase[i], hebin[i], Wp, WThi[i], WTlo[i], NDIM, NDIM, NDIM / 64, 2 };
      tb.start[i] = s; s += (NDIM / 64) * (NDIM / 64);
    }
    tb.d[6] = { x, nullptr, nullptr, xThi, xTlo, BDIM, NDIM, NDIM / 64, 1 };
    tb.start[6] = s; s += (BDIM / 64) * (NDIM / 64);
    tb.start[7] = s; tb.n = 7;
    transpose_k<<<s, 256, 0, stream>>>(tb);
  }

  auto fwdDesc = [&](const unsigned short* ahi, const unsigned short* alo, int wi) -> GemmDesc {
    GemmDesc d{};
    d.Ahi = ahi; d.Alo = alo; d.Bhi = WThi[wi]; d.Blo = WTlo[wi];
    d.lda = NDIM; d.ldb = NDIM; d.nk = NDIM / 64;
    return d;
  };
  auto hebPart = [&](const unsigned short* ahi, const unsigned short* alo,
                     const unsigned short* bhi, const unsigned short* blo,
                     int koff, int klen, float* partOut) -> GemmDesc {
    GemmDesc d{};
    d.Ahi = ahi + koff; d.Alo = alo + koff;
    d.Bhi = bhi + koff; d.Blo = blo + koff;
    d.lda = BDIM; d.ldb = BDIM; d.nk = klen / 64;
    d.out32a = partOut;
    return d;
  };
  auto hebRed = [&](int hi, const float* q0, const float* q1, const float* q2,
                    const float* q3, const float* q4, const float* q5,
                    const float* q6, const float* q7, int np) {
    HebRed r{};
    r.heb_in = hebin[hi]; r.out = hebout[hi];
    r.p[0]=q0; r.p[1]=q1; r.p[2]=q2; r.p[3]=q3; r.p[4]=q4; r.p[5]=q5; r.p[6]=q6; r.p[7]=q7;
    r.np = np;
    hebred_k<<<1024, 256, 0, stream>>>(r);
  };

  // ---- s3: h0x, h1x, yx  (768 blocks = 3/CU, 32 steps each) ----
  {
    GemmBatch gb{};
    gb.d[0] = fwdDesc(xhi, xlo, 0);
    gb.d[0].out32a = F0; gb.d[0].sp_hi = h0hi; gb.d[0].sp_lo = h0lo;
    gb.d[1] = fwdDesc(xhi, xlo, 1);
    gb.d[1].out32a = F1;
    gb.d[2] = fwdDesc(xhi, xlo, 3);
    gb.d[2].out32a = F2; gb.d[2].out32b = F3; gb.d[2].accadd = 0;
    gb.start[0] = 0; gb.start[1] = 256; gb.start[2] = 512; gb.start[3] = 768;
    gb.n = 3;
    gemm_k<<<768, 256, 0, stream>>>(gb);
  }

  // ---- s4: fT0=h0x^T, fT1=h1x^T, fT3=yx^T (splits); h0T hi/lo ----
  {
    TBatch tb{};
    tb.d[0] = { F0, nullptr, nullptr, R4, R4 + E, BDIM, NDIM, NDIM / 64, 1 };
    tb.d[1] = { F1, nullptr, nullptr, R5, R5 + E, BDIM, NDIM, NDIM / 64, 1 };
    tb.d[2] = { F2, nullptr, nullptr, R6, R6 + E, BDIM, NDIM, NDIM / 64, 1 };
    tb.d[3] = { h0hi, nullptr, nullptr, h0Thi, nullptr, BDIM, NDIM, NDIM / 64, 0 };
    tb.d[4] = { h0lo, nullptr, nullptr, h0Tlo, nullptr, BDIM, NDIM, NDIM / 64, 0 };
    for (int i = 0; i < 6; ++i) tb.start[i] = i * 1024;
    tb.n = 5;
    transpose_k<<<5120, 256, 0, stream>>>(tb);
  }

  // ---- s5: heb{x2h0,x2h1,x2y} 2-way split-K + h10, y0  (896 blocks) ----
  {
    float* px0a = (float*)WThi[0]; float* px0b = hebout[0];
    float* px1a = (float*)WThi[1]; float* px1b = hebout[1];
    float* pxya = (float*)WThi[3]; float* pxyb = hebout[3];
    GemmBatch gb{};
    gb.d[0] = hebPart(xThi, xTlo, R4, R4 + E, 0,    2048, px0a);
    gb.d[1] = hebPart(xThi, xTlo, R4, R4 + E, 2048, 2048, px0b);
    gb.d[2] = hebPart(xThi, xTlo, R5, R5 + E, 0,    2048, px1a);
    gb.d[3] = hebPart(xThi, xTlo, R5, R5 + E, 2048, 2048, px1b);
    gb.d[4] = hebPart(xThi, xTlo, R6, R6 + E, 0,    2048, pxya);
    gb.d[5] = hebPart(xThi, xTlo, R6, R6 + E, 2048, 2048, pxyb);
    gb.d[6] = fwdDesc(h0hi, h0lo, 2);                     // h1_0
    gb.d[6].out32a = F0; gb.d[6].addin = F1; gb.d[6].sp_hi = R0; gb.d[6].sp_lo = R0 + E;
    gb.d[7] = fwdDesc(h0hi, h0lo, 4);                     // y0
    gb.d[7].out32a = F2; gb.d[7].out32b = F3; gb.d[7].accadd = 1;
    for (int i = 0; i < 6; ++i) gb.start[i] = i * 64;
    gb.start[6] = 384; gb.start[7] = 640; gb.start[8] = 896;
    gb.n = 8;
    gemm_k<<<896, 256, 0, stream>>>(gb);
    hebRed(0, px0a, px0b, 0,0,0,0,0,0, 2);
    hebRed(1, px1a, px1b, 0,0,0,0,0,0, 2);
    hebRed(3, pxya, pxyb, 0,0,0,0,0,0, 2);
  }

  // ---- s6: fT2=h10^T, fT4=y0^T (splits); h1T hi/lo into R1 ----
  {
    TBatch tb{};
    tb.d[0] = { F0, nullptr, nullptr, R4, R4 + E, BDIM, NDIM, NDIM / 64, 1 };
    tb.d[1] = { F2, nullptr, nullptr, R5, R5 + E, BDIM, NDIM, NDIM / 64, 1 };
    tb.d[2] = { R0, nullptr, nullptr, R1, nullptr, BDIM, NDIM, NDIM / 64, 0 };
    tb.d[3] = { R0 + E, nullptr, nullptr, R1 + E, nullptr, BDIM, NDIM, NDIM / 64, 0 };
    for (int i = 0; i < 5; ++i) tb.start[i] = i * 1024;
    tb.n = 4;
    transpose_k<<<4096, 256, 0, stream>>>(tb);
  }

  // ---- s7: heb{h02h1,h02y} 4-way split-K + y1  (768 blocks) ----
  {
    float* pa[4] = { (float*)WThi[0], (float*)WThi[1], (float*)WThi[2], (float*)WThi[3] };
    float* pb[4] = { (float*)R6, (float*)R6 + 1048576, (float*)R6 + 2097152, (float*)R6 + 3145728 };
    GemmBatch gb{};
    for (int h = 0; h < 4; ++h) {
      gb.d[h]     = hebPart(h0Thi, h0Tlo, R4, R4 + E, h * 1024, 1024, pa[h]); // h02h1
      gb.d[4 + h] = hebPart(h0Thi, h0Tlo, R5, R5 + E, h * 1024, 1024, pb[h]); // h02y
    }
    gb.d[8] = fwdDesc(R0, R0 + E, 5);                     // y1 (A = h1 pair)
    gb.d[8].out32a = F1; gb.d[8].out32b = F3; gb.d[8].accadd = 1;
    for (int i = 0; i < 8; ++i) gb.start[i] = i * 64;
    gb.start[8] = 512; gb.start[9] = 768;
    gb.n = 9;
    gemm_k<<<768, 256, 0, stream>>>(gb);
    hebRed(2, pa[0], pa[1], pa[2], pa[3], 0,0,0,0, 4);
    hebRed(4, pb[0], pb[1], pb[2], pb[3], 0,0,0,0, 4);
  }

  // ---- s8: fT5 = y1^T split into R2 ----
  {
    TBatch tb{};
    tb.d[0] = { F1, nullptr, nullptr, R2, R2 + E, BDIM, NDIM, NDIM / 64, 1 };
    tb.start[0] = 0; tb.start[1] = 1024; tb.n = 1;
    transpose_k<<<1024, 256, 0, stream>>>(tb);
  }

  // ---- s9: heb_h12y 8-way split-K (512 blocks, 8 steps each) ----
  {
    GemmBatch gb{};
    for (int h = 0; h < 8; ++h)
      gb.d[h] = hebPart(R1, R1 + E, R2, R2 + E, h * 512, 512, part + (size_t)h * 1048576);
    for (int i = 0; i <= 8; ++i) gb.start[i] = i * 64;
    gb.n = 8;
    gemm_k<<<512, 256, 0, stream>>>(gb);
    hebRed(5, part, part + 1048576, part + 2097152, part + 3145728,
           part + 4194304, part + 5242880, part + 6291456, part + 7340032, 8);
  }

  // ---- s10: y assembly, tanh means ----
  yassm_k<<<2048, 256, 0, stream>>>(F3, out);
  tanhcol_k<<<16, 256, 0, stream>>>(F3, wpart, dpart);
  finalize_k<<<1, 64, 0, stream>>>(wpart, dpart, out, out_size);
}

// Round 15
// 485.480 us; speedup vs baseline: 1.3271x; 1.0326x over previous
//
#include <hip/hip_runtime.h>
#include <stdint.h>

#define ALPHA 0.3f
#define CLAMPV 0.3f
#define BDIM 4096
#define NDIM 1024

typedef float f32x4 __attribute__((ext_vector_type(4)));
typedef __bf16 bf16x8 __attribute__((ext_vector_type(8)));

union U16x8 { uint4 v; unsigned short u[8]; };

__device__ __forceinline__ float bf2f(unsigned short u) {
  union { unsigned int i; float f; } c; c.i = ((unsigned int)u) << 16; return c.f;
}
__device__ __forceinline__ unsigned short f2bf(float f) {
  union { float f; unsigned int i; } c; c.f = f;
  unsigned int u = c.i;
  unsigned int r = u + 0x7FFFu + ((u >> 16) & 1u);
  return (unsigned short)(r >> 16);
}

// ---------------------------------------------------------------------------
__global__ __launch_bounds__(256) void fill_k(float* __restrict__ out, int n) {
  int i = blockIdx.x * 256 + threadIdx.x;
  if (i < n) out[i] = 12345.0f;
}

// ---------------------------------------------------------------------------
__global__ __launch_bounds__(256) void split_x_k(const float* __restrict__ x,
                                                 unsigned short* __restrict__ hi,
                                                 unsigned short* __restrict__ lo) {
  const size_t i0 = ((size_t)blockIdx.x * 256 + threadIdx.x) * 8;
  f32x4 a = *(const f32x4*)(x + i0);
  f32x4 b = *(const f32x4*)(x + i0 + 4);
  U16x8 h8, l8;
#pragma unroll
  for (int i = 0; i < 4; ++i) {
    unsigned short h = f2bf(a[i]); h8.u[i] = h; l8.u[i] = f2bf(a[i] - bf2f(h));
    unsigned short h2 = f2bf(b[i]); h8.u[4+i] = h2; l8.u[4+i] = f2bf(b[i] - bf2f(h2));
  }
  *(uint4*)(hi + i0) = h8.v;
  *(uint4*)(lo + i0) = l8.v;
}

// ---------------------------------------------------------------------------
// batched tiled transpose
// ---------------------------------------------------------------------------
struct TDesc {
  const void* in1; const void* in2; const float* Wp;
  unsigned short* out_hi; unsigned short* out_lo;
  int R, C, tilesC, mode;
};
struct TBatch { TDesc d[8]; int start[9]; int n; };

__global__ __launch_bounds__(256) void transpose_k(TBatch batch) {
  const int bid = blockIdx.x;
  int g = 0;
#pragma unroll
  for (int i = 1; i < 8; ++i)
    if (i < batch.n && bid >= batch.start[i]) g = i;
  TDesc D = batch.d[g];
  const int lt = bid - batch.start[g];
  const int trow = lt / D.tilesC;
  const int tcol = lt - trow * D.tilesC;
  const int r0 = trow * 64, c0 = tcol * 64;

  __shared__ float tile[64][65];
  const int t = threadIdx.x;
  const int sub = t >> 3, oct = t & 7;
  const float Wv = (D.mode == 2) ? *D.Wp : 0.f;

#pragma unroll
  for (int p = 0; p < 2; ++p) {
    const int rl = p * 32 + sub;
    const int cl0 = oct * 8;
    float vv[8];
    if (D.mode == 0) {
      const unsigned short* ip = (const unsigned short*)D.in1 + (size_t)(r0 + rl) * D.C + c0 + cl0;
      U16x8 tmp; tmp.v = *(const uint4*)ip;
#pragma unroll
      for (int i = 0; i < 8; ++i) vv[i] = bf2f(tmp.u[i]);
    } else {
      const float* ip = (const float*)D.in1 + (size_t)(r0 + rl) * D.C + c0 + cl0;
      f32x4 a = *(const f32x4*)ip, b = *(const f32x4*)(ip + 4);
#pragma unroll
      for (int i = 0; i < 4; ++i) { vv[i] = a[i]; vv[4+i] = b[i]; }
      if (D.mode == 2) {
        const float* ip2 = (const float*)D.in2 + (size_t)(r0 + rl) * D.C + c0 + cl0;
        f32x4 c = *(const f32x4*)ip2, d2 = *(const f32x4*)(ip2 + 4);
#pragma unroll
        for (int i = 0; i < 4; ++i) { vv[i] += Wv * c[i]; vv[4+i] += Wv * d2[i]; }
      }
    }
#pragma unroll
    for (int i = 0; i < 8; ++i) tile[cl0 + i][rl] = vv[i];
  }
  __syncthreads();
#pragma unroll
  for (int p = 0; p < 2; ++p) {
    const int cl = p * 32 + sub;
    const int rl0 = oct * 8;
    U16x8 h8, l8;
#pragma unroll
    for (int i = 0; i < 8; ++i) {
      float v = tile[cl][rl0 + i];
      unsigned short h = f2bf(v);
      h8.u[i] = h;
      l8.u[i] = f2bf(v - bf2f(h));
    }
    const size_t o = (size_t)(c0 + cl) * D.R + r0 + rl0;
    *(uint4*)(D.out_hi + o) = h8.v;
    if (D.mode != 0) *(uint4*)(D.out_lo + o) = l8.v;
  }
}

// ---------------------------------------------------------------------------
// shared GEMM descriptor (both kernels)
// ---------------------------------------------------------------------------
struct GemmDesc {
  const unsigned short *Ahi, *Alo, *Bhi, *Blo;
  int lda, ldb, nk, accadd;
  float* out32a;
  float* out32b;
  const float* addin;
  unsigned short* sp_hi;
  unsigned short* sp_lo;
  const float* heb_in;
  float* heb_out;
};
struct GemmBatch { GemmDesc d[12]; int start[13]; int n; };
struct Gemm256Batch { GemmDesc d[8]; int start[9]; int n; };

#define AS1 __attribute__((address_space(1)))
#define AS3 __attribute__((address_space(3)))

// ---------------------------------------------------------------------------
// v4 kernel (128x128 tile, BK=64, single-buffered) — used for s3/s7/s9 whose
// grids (768/768/512) are exact multiples of the 3-blocks/CU capacity.
// nk = K/64 steps per phase.
// ---------------------------------------------------------------------------
__global__ __launch_bounds__(256) void gemm_k(GemmBatch batch) {
  const int bid = blockIdx.x;
  int g = 0;
#pragma unroll
  for (int i = 1; i < 12; ++i)
    if (i < batch.n && bid >= batch.start[i]) g = i;
  GemmDesc D = batch.d[g];
  const int local = bid - batch.start[g];
  const int tm = local >> 3;        // tilesN fixed at 8 (N=1024)
  const int tn = local & 7;

  __shared__ __align__(16) unsigned short As[128 * 64];    // 16 KB
  __shared__ __align__(16) unsigned short BsH[128 * 64];   // 16 KB
  __shared__ __align__(16) unsigned short BsL[128 * 64];   // 16 KB

  const int t = threadIdx.x;
  const int lane = t & 63;
  const int wave = t >> 6;
  const int wr = wave >> 1, wc = wave & 1;
  const int fr = lane & 15, fg = lane >> 4;

  const f32x4 vzero = {0.f, 0.f, 0.f, 0.f};
  f32x4 acc[4][4];
#pragma unroll
  for (int i = 0; i < 4; ++i)
#pragma unroll
    for (int j = 0; j < 4; ++j) acc[i][j] = vzero;

  const int srow = t >> 3;                                   // 0..31
  const int scolB = ((t & 7) << 4) ^ ((srow & 7) << 4);      // bytes in row
  const int scolE = scolB >> 1;                              // elems

  int aoff[4], boff[4];
#pragma unroll
  for (int i = 0; i < 4; ++i) {
    const int ra = wr * 64 + i * 16 + fr;
    aoff[i] = ra * 128 + ((fg << 4) ^ ((ra & 7) << 4));
    const int rb = wc * 64 + i * 16 + fr;
    boff[i] = rb * 128 + ((fg << 4) ^ ((rb & 7) << 4));
  }
  const char* Asb = (const char*)As;
  const char* BsHb = (const char*)BsH;
  const char* BsLb = (const char*)BsL;

  const size_t arow = (size_t)(tm * 128 + srow) * D.lda + scolE;
  const size_t brow = (size_t)(tn * 128 + srow) * D.ldb + scolE;
  const size_t astep = (size_t)32 * D.lda;
  const size_t bstep = (size_t)32 * D.ldb;

#pragma unroll 1
  for (int ph = 0; ph < 2; ++ph) {
    const unsigned short* Ap = ph ? D.Alo : D.Ahi;
#pragma unroll 1
    for (int kt = 0; kt < D.nk; ++kt) {
      const int kb = kt << 6;   // k-elem offset
#pragma unroll
      for (int q = 0; q < 4; ++q) {
        __builtin_amdgcn_global_load_lds(
            (const AS1 void*)(Ap + arow + q * astep + kb),
            (AS3 void*)(As + q * 2048 + wave * 512), 16, 0, 0);
        __builtin_amdgcn_global_load_lds(
            (const AS1 void*)(D.Bhi + brow + q * bstep + kb),
            (AS3 void*)(BsH + q * 2048 + wave * 512), 16, 0, 0);
      }
      if (ph == 0) {
#pragma unroll
        for (int q = 0; q < 4; ++q)
          __builtin_amdgcn_global_load_lds(
              (const AS1 void*)(D.Blo + brow + q * bstep + kb),
              (AS3 void*)(BsL + q * 2048 + wave * 512), 16, 0, 0);
      }
      __syncthreads();           // drain stage, rendezvous
#pragma unroll
      for (int s = 0; s < 2; ++s) {
        const int sx = s << 6;
        bf16x8 af[4];
#pragma unroll
        for (int i = 0; i < 4; ++i) af[i] = *(const bf16x8*)(Asb + (aoff[i] ^ sx));
#pragma unroll
        for (int j = 0; j < 4; ++j) {
          const bf16x8 bh = *(const bf16x8*)(BsHb + (boff[j] ^ sx));
#pragma unroll
          for (int i = 0; i < 4; ++i)
            acc[i][j] = __builtin_amdgcn_mfma_f32_16x16x32_bf16(af[i], bh, acc[i][j], 0, 0, 0);
          if (ph == 0) {
            const bf16x8 bl = *(const bf16x8*)(BsLb + (boff[j] ^ sx));
#pragma unroll
            for (int i = 0; i < 4; ++i)
              acc[i][j] = __builtin_amdgcn_mfma_f32_16x16x32_bf16(af[i], bl, acc[i][j], 0, 0, 0);
          }
        }
      }
      __syncthreads();           // all reads done before next stage
    }
  }

  const int grb = tm * 128 + wr * 64 + fg * 4;
  const int gcb = tn * 128 + wc * 64 + fr;
#pragma unroll
  for (int i = 0; i < 4; ++i) {
#pragma unroll
    for (int j = 0; j < 4; ++j) {
      const int gc = gcb + j * 16;
#pragma unroll
      for (int r = 0; r < 4; ++r) {
        const int gr = grb + i * 16 + r;
        const size_t idx = (size_t)gr * NDIM + gc;
        const float v = acc[i][j][r];
        if (D.heb_out) {
          D.heb_out[idx] = fminf(fmaxf(D.heb_in[idx] + ALPHA * v, -CLAMPV), CLAMPV);
        } else {
          if (D.out32a) D.out32a[idx] = v;
          if (D.out32b) D.out32b[idx] = D.accadd ? (D.out32b[idx] + v) : v;
          if (D.sp_hi) {
            float rv = v + (D.addin ? D.addin[idx] : 0.f);
            rv = fmaxf(rv, 0.f);
            const unsigned short h = f2bf(rv);
            D.sp_hi[idx] = h;
            D.sp_lo[idx] = f2bf(rv - bf2f(h));
          }
        }
      }
    }
  }
}

// ---------------------------------------------------------------------------
// v6 kernel (256x128 tile, BK=32, double-buffered, counted vmcnt 8/6/0) —
// used for s5 only (448 blocks). Measured r8/r10/r11: 150-151us @ 854 TF,
// absmax 0.125. nk = K/32 steps per phase. vmcnt counts = per-wave load
// counts (8 ph0 / 6 ph1): drains exactly the current tile, keeps the
// just-issued prefetch in flight (T4).
// ---------------------------------------------------------------------------
__global__ __launch_bounds__(256, 2) void gemm256_k(Gemm256Batch batch) {
  const int bid = blockIdx.x;
  int g = 0;
#pragma unroll
  for (int i = 1; i < 8; ++i)
    if (i < batch.n && bid >= batch.start[i]) g = i;
  GemmDesc D = batch.d[g];
  const int local = bid - batch.start[g];
  const int tm = local >> 3;        // tilesN fixed at 8 (N=1024)
  const int tn = local & 7;

  // 2 buffers x (A 16KB | Bhi 8KB | Blo 8KB) = 64 KB
  __shared__ __align__(16) unsigned short LDS[32768];

  const int t = threadIdx.x;
  const int lane = t & 63;
  const int wave = t >> 6;
  const int wr = wave >> 1, wc = wave & 1;
  const int fr = lane & 15, fg = lane >> 4;

  f32x4 acc[8][4];
#pragma unroll
  for (int i = 0; i < 8; ++i)
#pragma unroll
    for (int j = 0; j < 4; ++j)
#pragma unroll
      for (int rr = 0; rr < 4; ++rr) acc[i][j][rr] = 0.f;

  const int r0 = t >> 2;                                    // 0..63
  const int colSwE = (((t & 3) ^ ((t >> 3) & 3)) << 3);     // element offset

  size_t aRow[4], bRow[2];
#pragma unroll
  for (int qq = 0; qq < 4; ++qq)
    aRow[qq] = (size_t)(tm * 256 + qq * 64 + r0) * D.lda + colSwE;
#pragma unroll
  for (int qq = 0; qq < 2; ++qq)
    bRow[qq] = (size_t)(tn * 128 + qq * 64 + r0) * D.ldb + colSwE;

  const int ldsW = wave * 512;    // wave-uniform elem offset within region

  auto stageA = [&](const unsigned short* P, int kb, int b) {
    unsigned short* base = LDS + b * 16384 + ldsW;
#pragma unroll
    for (int qq = 0; qq < 4; ++qq)
      __builtin_amdgcn_global_load_lds(
          (const AS1 void*)(P + aRow[qq] + kb),
          (AS3 void*)(base + qq * 2048), 16, 0, 0);
  };
  auto stageB = [&](const unsigned short* P, int region, int kb, int b) {
    unsigned short* base = LDS + b * 16384 + region + ldsW;
#pragma unroll
    for (int qq = 0; qq < 2; ++qq)
      __builtin_amdgcn_global_load_lds(
          (const AS1 void*)(P + bRow[qq] + kb),
          (AS3 void*)(base + qq * 2048), 16, 0, 0);
  };

  const int swz = ((fg ^ ((fr >> 1) & 3)) << 4);
  int aoff[8], boff[4];
#pragma unroll
  for (int i = 0; i < 8; ++i)
    aoff[i] = (wr * 128 + i * 16 + fr) * 64 + swz;
#pragma unroll
  for (int j = 0; j < 4; ++j)
    boff[j] = 16384 + (wc * 64 + j * 16 + fr) * 64 + swz;
  const char* ldsc = (const char*)LDS;

  auto computePh0 = [&](int b) {
    const char* bb = ldsc + b * 32768;
    bf16x8 af[8];
#pragma unroll
    for (int i = 0; i < 8; ++i) af[i] = *(const bf16x8*)(bb + aoff[i]);
#pragma unroll
    for (int j = 0; j < 4; ++j) {
      const bf16x8 bh = *(const bf16x8*)(bb + boff[j]);
#pragma unroll
      for (int i = 0; i < 8; ++i)
        acc[i][j] = __builtin_amdgcn_mfma_f32_16x16x32_bf16(af[i], bh, acc[i][j], 0, 0, 0);
      const bf16x8 bl = *(const bf16x8*)(bb + boff[j] + 8192);
#pragma unroll
      for (int i = 0; i < 8; ++i)
        acc[i][j] = __builtin_amdgcn_mfma_f32_16x16x32_bf16(af[i], bl, acc[i][j], 0, 0, 0);
    }
  };
  auto computePh1 = [&](int b) {
    const char* bb = ldsc + b * 32768;
    bf16x8 af[8];
#pragma unroll
    for (int i = 0; i < 8; ++i) af[i] = *(const bf16x8*)(bb + aoff[i]);
#pragma unroll
    for (int j = 0; j < 4; ++j) {
      const bf16x8 bh = *(const bf16x8*)(bb + boff[j]);
#pragma unroll
      for (int i = 0; i < 8; ++i)
        acc[i][j] = __builtin_amdgcn_mfma_f32_16x16x32_bf16(af[i], bh, acc[i][j], 0, 0, 0);
    }
  };

  const int n = D.nk;

  // prologue: stage step 0 of phase 0 into buffer 0 (8 loads/wave)
  stageA(D.Ahi, 0, 0);
  stageB(D.Bhi, 8192, 0, 0);
  stageB(D.Blo, 12288, 0, 0);
  int buf = 0;

  // phase 0
#pragma unroll 1
  for (int kt = 0; kt < n; ++kt) {
    if (kt + 1 < n) {
      const int kb = (kt + 1) << 5;
      stageA(D.Ahi, kb, buf ^ 1);
      stageB(D.Bhi, 8192, kb, buf ^ 1);
      stageB(D.Blo, 12288, kb, buf ^ 1);
      asm volatile("s_waitcnt vmcnt(8)" ::: "memory");  // drain cur tile, keep 8 prefetch
    } else {
      stageA(D.Alo, 0, buf ^ 1);        // first step of phase 1 (6 loads/wave)
      stageB(D.Bhi, 8192, 0, buf ^ 1);
      asm volatile("s_waitcnt vmcnt(6)" ::: "memory");  // drain cur tile, keep 6 prefetch
    }
    __builtin_amdgcn_s_barrier();
    __builtin_amdgcn_sched_barrier(0);
    computePh0(buf);
    __builtin_amdgcn_sched_barrier(0);
    __builtin_amdgcn_s_barrier();
    buf ^= 1;
  }

  // phase 1
#pragma unroll 1
  for (int kt = 0; kt < n; ++kt) {
    if (kt + 1 < n) {
      const int kb = (kt + 1) << 5;
      stageA(D.Alo, kb, buf ^ 1);
      stageB(D.Bhi, 8192, kb, buf ^ 1);
      asm volatile("s_waitcnt vmcnt(6)" ::: "memory");  // drain cur tile, keep 6 prefetch
    } else {
      asm volatile("s_waitcnt vmcnt(0)" ::: "memory");
    }
    __builtin_amdgcn_s_barrier();
    __builtin_amdgcn_sched_barrier(0);
    computePh1(buf);
    __builtin_amdgcn_sched_barrier(0);
    __builtin_amdgcn_s_barrier();
    buf ^= 1;
  }

  // epilogue
  const int grb = tm * 256 + wr * 128 + fg * 4;
  const int gcb = tn * 128 + wc * 64 + fr;
#pragma unroll
  for (int i = 0; i < 8; ++i) {
#pragma unroll
    for (int j = 0; j < 4; ++j) {
      const int gc = gcb + j * 16;
#pragma unroll
      for (int rr = 0; rr < 4; ++rr) {
        const int gr = grb + i * 16 + rr;
        const size_t idx = (size_t)gr * NDIM + gc;
        const float v = acc[i][j][rr];
        if (D.heb_out) {
          D.heb_out[idx] = fminf(fmaxf(D.heb_in[idx] + ALPHA * v, -CLAMPV), CLAMPV);
        } else {
          if (D.out32a) D.out32a[idx] = v;
          if (D.out32b) D.out32b[idx] = D.accadd ? (D.out32b[idx] + v) : v;
          if (D.sp_hi) {
            float rv = v + (D.addin ? D.addin[idx] : 0.f);
            rv = fmaxf(rv, 0.f);
            const unsigned short h = f2bf(rv);
            D.sp_hi[idx] = h;
            D.sp_lo[idx] = f2bf(rv - bf2f(h));
          }
        }
      }
    }
  }
}

// ---------------------------------------------------------------------------
// heb output from up to 8 split-K partials: out = clamp(heb_in + ALPHA*sum)
// ---------------------------------------------------------------------------
struct HebRed { const float* heb_in; float* out; const float* p[8]; int np; };

__global__ __launch_bounds__(256) void hebred_k(HebRed R) {
  const size_t i0 = ((size_t)blockIdx.x * 256 + threadIdx.x) * 4;
  f32x4 s = *(const f32x4*)(R.p[0] + i0);
#pragma unroll
  for (int k = 1; k < 8; ++k)
    if (k < R.np) s += *(const f32x4*)(R.p[k] + i0);
  f32x4 h = *(const f32x4*)(R.heb_in + i0);
  f32x4 o;
#pragma unroll
  for (int i = 0; i < 4; ++i) o[i] = fminf(fmaxf(h[i] + ALPHA * s[i], -CLAMPV), CLAMPV);
  *(f32x4*)(R.out + i0) = o;
}

// ---------------------------------------------------------------------------
__global__ __launch_bounds__(256) void yassm_k(const float* __restrict__ ysum,
                                               float* __restrict__ yout) {
  const int stride = gridDim.x * 256;
  for (int idx = blockIdx.x * 256 + threadIdx.x; idx < BDIM * 1022; idx += stride) {
    const int row = idx / 1022;
    const int col = idx - row * 1022;
    yout[idx] = ysum[(size_t)row * NDIM + col];
  }
}

__global__ __launch_bounds__(256) void tanhcol_k(const float* __restrict__ ysum,
                                                 float* __restrict__ wpart,
                                                 float* __restrict__ dpart) {
  const int r = blockIdx.x * 256 + threadIdx.x;
  const size_t b = (size_t)r * NDIM;
  float tw = tanhf(ysum[b + 1022]);
  float td = tanhf(ysum[b + 1021]);
#pragma unroll
  for (int o = 32; o > 0; o >>= 1) { tw += __shfl_down(tw, o); td += __shfl_down(td, o); }
  __shared__ float s1[4], s2[4];
  const int lane = threadIdx.x & 63, wv = threadIdx.x >> 6;
  if (lane == 0) { s1[wv] = tw; s2[wv] = td; }
  __syncthreads();
  if (threadIdx.x == 0) {
    wpart[blockIdx.x] = s1[0] + s1[1] + s1[2] + s1[3];
    dpart[blockIdx.x] = s2[0] + s2[1] + s2[2] + s2[3];
  }
}

__global__ void finalize_k(const float* __restrict__ wpart, const float* __restrict__ dpart,
                           float* __restrict__ out, int nout) {
  if (threadIdx.x == 0 && blockIdx.x == 0) {
    float s = 0.f, d = 0.f;
    for (int i = 0; i < 16; ++i) { s += wpart[i]; d += dpart[i]; }
    out[nout - 2] = s * (1.f / BDIM);
    out[nout - 1] = d * (1.f / BDIM);
  }
}

// ---------------------------------------------------------------------------
extern "C" void kernel_launch(void* const* d_in, const int* in_sizes, int n_in,
                              void* d_out, int out_size, void* d_ws, size_t ws_size,
                              hipStream_t stream) {
  const float* x = (const float*)d_in[0];
  const float* wbase[6]; const float* hebin[6];
  for (int i = 0; i < 6; ++i) { wbase[i] = (const float*)d_in[1 + i]; hebin[i] = (const float*)d_in[7 + i]; }
  const float* Wp = (const float*)d_in[13];
  float* out = (float*)d_out;
  const size_t YOUT = (size_t)BDIM * 1022;
  float* hebout[6];
  for (int i = 0; i < 6; ++i) hebout[i] = out + YOUT + (size_t)i * 1048576;

  // ---- workspace layout: 200 MiB, lifetime-aliased regions ----
  const size_t E = (size_t)BDIM * NDIM;
  const size_t PAIRB = E * 4;                    // hi+lo bf16 pair (16 MiB)
  const size_t WPAIRB = (size_t)NDIM * NDIM * 4; // weight hi+lo pair (4 MiB)
  const size_t FB = E * 4;                       // f32 buffer (16 MiB)
  const size_t REQUIRED = 7 * PAIRB + 6 * WPAIRB + 4 * FB;

  if (ws_size < REQUIRED) {
    fill_k<<<(out_size + 255) / 256, 256, 0, stream>>>(out, out_size);
    return;
  }

  char* p = (char*)d_ws;
  auto takeB = [&](size_t n) -> char* { char* q = p; p += n; return q; };

  unsigned short* R0 = (unsigned short*)takeB(PAIRB);   // x pair -> h1 pair
  unsigned short* R1 = (unsigned short*)takeB(PAIRB);   // xT pair -> h1T pair
  unsigned short* R2 = (unsigned short*)takeB(PAIRB);   // h0 pair -> fT5 pair
  unsigned short* R3 = (unsigned short*)takeB(PAIRB);   // h0T pair
  unsigned short* R4 = (unsigned short*)takeB(PAIRB);   // fT0 -> fT2 -> h12y parts 0-3
  unsigned short* R5 = (unsigned short*)takeB(PAIRB);   // fT1 -> fT4 -> h12y parts 4-7
  unsigned short* R6 = (unsigned short*)takeB(PAIRB);   // fT3 -> h02y parts -> wpart
  unsigned short* WThi[6]; unsigned short* WTlo[6];
  for (int i = 0; i < 6; ++i) {
    WThi[i] = (unsigned short*)takeB(WPAIRB);
    WTlo[i] = WThi[i] + (size_t)NDIM * NDIM;
  }
  float* F0 = (float*)takeB(FB);   // h0x -> h10
  float* F1 = (float*)takeB(FB);   // h1x -> y1tmp
  float* F2 = (float*)takeB(FB);   // yxtmp -> y0tmp
  float* F3 = (float*)takeB(FB);   // ysum (live to end)

  unsigned short *xhi = R0, *xlo = R0 + E;
  unsigned short *xThi = R1, *xTlo = R1 + E;
  unsigned short *h0hi = R2, *h0lo = R2 + E;
  unsigned short *h0Thi = R3, *h0Tlo = R3 + E;
  float* part = (float*)R4;        // h12y: 8 x 1M f32 spans R4+R5
  float* wpart = (float*)R6; float* dpart = wpart + 64;

  // ---- s1: split x ----
  split_x_k<<<2048, 256, 0, stream>>>(x, xhi, xlo);

  // ---- s2: Weff^T splits (6) + x^T split ----
  {
    TBatch tb{};
    int s = 0;
    for (int i = 0; i < 6; ++i) {
      tb.d[i] = { wbase[i], hebin[i], Wp, WThi[i], WTlo[i], NDIM, NDIM, NDIM / 64, 2 };
      tb.start[i] = s; s += (NDIM / 64) * (NDIM / 64);
    }
    tb.d[6] = { x, nullptr, nullptr, xThi, xTlo, BDIM, NDIM, NDIM / 64, 1 };
    tb.start[6] = s; s += (BDIM / 64) * (NDIM / 64);
    tb.start[7] = s; tb.n = 7;
    transpose_k<<<s, 256, 0, stream>>>(tb);
  }

  auto fwdDesc = [&](const unsigned short* ahi, const unsigned short* alo, int wi, int bk) -> GemmDesc {
    GemmDesc d{};
    d.Ahi = ahi; d.Alo = alo; d.Bhi = WThi[wi]; d.Blo = WTlo[wi];
    d.lda = NDIM; d.ldb = NDIM; d.nk = NDIM / bk;
    return d;
  };
  auto hebPart = [&](const unsigned short* ahi, const unsigned short* alo,
                     const unsigned short* bhi, const unsigned short* blo,
                     int koff, int klen, float* partOut, int bk) -> GemmDesc {
    GemmDesc d{};
    d.Ahi = ahi + koff; d.Alo = alo + koff;
    d.Bhi = bhi + koff; d.Blo = blo + koff;
    d.lda = BDIM; d.ldb = BDIM; d.nk = klen / bk;
    d.out32a = partOut;
    return d;
  };
  auto hebRed = [&](int hi, const float* q0, const float* q1, const float* q2,
                    const float* q3, const float* q4, const float* q5,
                    const float* q6, const float* q7, int np) {
    HebRed r{};
    r.heb_in = hebin[hi]; r.out = hebout[hi];
    r.p[0]=q0; r.p[1]=q1; r.p[2]=q2; r.p[3]=q3; r.p[4]=q4; r.p[5]=q5; r.p[6]=q6; r.p[7]=q7;
    r.np = np;
    hebred_k<<<1024, 256, 0, stream>>>(r);
  };

  // ---- s3: h0x, h1x, yx  (v4, 768 blocks = 3/CU exact) ----
  {
    GemmBatch gb{};
    gb.d[0] = fwdDesc(xhi, xlo, 0, 64);
    gb.d[0].out32a = F0; gb.d[0].sp_hi = h0hi; gb.d[0].sp_lo = h0lo;
    gb.d[1] = fwdDesc(xhi, xlo, 1, 64);
    gb.d[1].out32a = F1;
    gb.d[2] = fwdDesc(xhi, xlo, 3, 64);
    gb.d[2].out32a = F2; gb.d[2].out32b = F3; gb.d[2].accadd = 0;
    gb.start[0] = 0; gb.start[1] = 256; gb.start[2] = 512; gb.start[3] = 768;
    gb.n = 3;
    gemm_k<<<768, 256, 0, stream>>>(gb);
  }

  // ---- s4: fT0=h0x^T, fT1=h1x^T, fT3=yx^T (splits); h0T hi/lo ----
  {
    TBatch tb{};
    tb.d[0] = { F0, nullptr, nullptr, R4, R4 + E, BDIM, NDIM, NDIM / 64, 1 };
    tb.d[1] = { F1, nullptr, nullptr, R5, R5 + E, BDIM, NDIM, NDIM / 64, 1 };
    tb.d[2] = { F2, nullptr, nullptr, R6, R6 + E, BDIM, NDIM, NDIM / 64, 1 };
    tb.d[3] = { h0hi, nullptr, nullptr, h0Thi, nullptr, BDIM, NDIM, NDIM / 64, 0 };
    tb.d[4] = { h0lo, nullptr, nullptr, h0Tlo, nullptr, BDIM, NDIM, NDIM / 64, 0 };
    for (int i = 0; i < 6; ++i) tb.start[i] = i * 1024;
    tb.n = 5;
    transpose_k<<<5120, 256, 0, stream>>>(tb);
  }

  // ---- s5: heb{x2h0,x2h1,x2y} 2-way split-K + h10, y0  (v6, 448 blocks) ----
  // v6 256-tile: heb desc = 32 blocks, fwd desc = 128 blocks. Measured
  // r8/r10/r11 at this exact batch: 150-151 us, absmax 0.125.
  {
    float* px0a = (float*)WThi[0]; float* px0b = hebout[0];
    float* px1a = (float*)WThi[1]; float* px1b = hebout[1];
    float* pxya = (float*)WThi[3]; float* pxyb = hebout[3];
    Gemm256Batch gb{};
    gb.d[0] = hebPart(xThi, xTlo, R4, R4 + E, 0,    2048, px0a, 32);
    gb.d[1] = hebPart(xThi, xTlo, R4, R4 + E, 2048, 2048, px0b, 32);
    gb.d[2] = hebPart(xThi, xTlo, R5, R5 + E, 0,    2048, px1a, 32);
    gb.d[3] = hebPart(xThi, xTlo, R5, R5 + E, 2048, 2048, px1b, 32);
    gb.d[4] = hebPart(xThi, xTlo, R6, R6 + E, 0,    2048, pxya, 32);
    gb.d[5] = hebPart(xThi, xTlo, R6, R6 + E, 2048, 2048, pxyb, 32);
    gb.d[6] = fwdDesc(h0hi, h0lo, 2, 32);                 // h1_0
    gb.d[6].out32a = F0; gb.d[6].addin = F1; gb.d[6].sp_hi = R0; gb.d[6].sp_lo = R0 + E;
    gb.d[7] = fwdDesc(h0hi, h0lo, 4, 32);                 // y0
    gb.d[7].out32a = F2; gb.d[7].out32b = F3; gb.d[7].accadd = 1;
    for (int i = 0; i < 6; ++i) gb.start[i] = i * 32;
    gb.start[6] = 192; gb.start[7] = 320; gb.start[8] = 448;
    gb.n = 8;
    gemm256_k<<<448, 256, 0, stream>>>(gb);
    hebRed(0, px0a, px0b, 0,0,0,0,0,0, 2);
    hebRed(1, px1a, px1b, 0,0,0,0,0,0, 2);
    hebRed(3, pxya, pxyb, 0,0,0,0,0,0, 2);
  }

  // ---- s6: fT2=h10^T, fT4=y0^T (splits); h1T hi/lo into R1 ----
  {
    TBatch tb{};
    tb.d[0] = { F0, nullptr, nullptr, R4, R4 + E, BDIM, NDIM, NDIM / 64, 1 };
    tb.d[1] = { F2, nullptr, nullptr, R5, R5 + E, BDIM, NDIM, NDIM / 64, 1 };
    tb.d[2] = { R0, nullptr, nullptr, R1, nullptr, BDIM, NDIM, NDIM / 64, 0 };
    tb.d[3] = { R0 + E, nullptr, nullptr, R1 + E, nullptr, BDIM, NDIM, NDIM / 64, 0 };
    for (int i = 0; i < 5; ++i) tb.start[i] = i * 1024;
    tb.n = 4;
    transpose_k<<<4096, 256, 0, stream>>>(tb);
  }

  // ---- s7: heb{h02h1,h02y} 4-way split-K + y1  (v4, 768 blocks = 3/CU) ----
  {
    float* pa[4] = { (float*)WThi[0], (float*)WThi[1], (float*)WThi[2], (float*)WThi[3] };
    float* pb[4] = { (float*)R6, (float*)R6 + 1048576, (float*)R6 + 2097152, (float*)R6 + 3145728 };
    GemmBatch gb{};
    for (int h = 0; h < 4; ++h) {
      gb.d[h]     = hebPart(h0Thi, h0Tlo, R4, R4 + E, h * 1024, 1024, pa[h], 64); // h02h1
      gb.d[4 + h] = hebPart(h0Thi, h0Tlo, R5, R5 + E, h * 1024, 1024, pb[h], 64); // h02y
    }
    gb.d[8] = fwdDesc(R0, R0 + E, 5, 64);                 // y1 (A = h1 pair)
    gb.d[8].out32a = F1; gb.d[8].out32b = F3; gb.d[8].accadd = 1;
    for (int i = 0; i < 8; ++i) gb.start[i] = i * 64;
    gb.start[8] = 512; gb.start[9] = 768;
    gb.n = 9;
    gemm_k<<<768, 256, 0, stream>>>(gb);
    hebRed(2, pa[0], pa[1], pa[2], pa[3], 0,0,0,0, 4);
    hebRed(4, pb[0], pb[1], pb[2], pb[3], 0,0,0,0, 4);
  }

  // ---- s8: fT5 = y1^T split into R2 ----
  {
    TBatch tb{};
    tb.d[0] = { F1, nullptr, nullptr, R2, R2 + E, BDIM, NDIM, NDIM / 64, 1 };
    tb.start[0] = 0; tb.start[1] = 1024; tb.n = 1;
    transpose_k<<<1024, 256, 0, stream>>>(tb);
  }

  // ---- s9: heb_h12y 8-way split-K (v4, 512 blocks = 2/CU) ----
  {
    GemmBatch gb{};
    for (int h = 0; h < 8; ++h)
      gb.d[h] = hebPart(R1, R1 + E, R2, R2 + E, h * 512, 512, part + (size_t)h * 1048576, 64);
    for (int i = 0; i <= 8; ++i) gb.start[i] = i * 64;
    gb.n = 8;
    gemm_k<<<512, 256, 0, stream>>>(gb);
    hebRed(5, part, part + 1048576, part + 2097152, part + 3145728,
           part + 4194304, part + 5242880, part + 6291456, part + 7340032, 8);
  }

  // ---- s10: y assembly, tanh means ----
  yassm_k<<<2048, 256, 0, stream>>>(F3, out);
  tanhcol_k<<<16, 256, 0, stream>>>(F3, wpart, dpart);
  finalize_k<<<1, 64, 0, stream>>>(wpart, dpart, out, out_size);
}